// Round 2
// baseline (959.841 us; speedup 1.0000x reference)
//
#include <hip/hip_runtime.h>

#define N_NODES 100000
#define N_EDGES 1600000
#define NFEAT   128
#define HID     128
#define NG      256
#define NCLS    8

// ---------------- CSR build ----------------

__global__ void zero_int_kernel(int* __restrict__ p, int n) {
    int i = blockIdx.x * 256 + threadIdx.x;
    if (i < n) p[i] = 0;
}

__global__ void count_deg_kernel(const int* __restrict__ dst, int* __restrict__ deg, int e) {
    int i = blockIdx.x * 256 + threadIdx.x;
    if (i < e) atomicAdd(&deg[dst[i]], 1);
}

__global__ void node_scalars_kernel(const int* __restrict__ deg_int,
                                    float* __restrict__ dinv,
                                    float* __restrict__ deg_inv, int n) {
    int i = blockIdx.x * 256 + threadIdx.x;
    if (i < n) {
        float d = (float)deg_int[i] + 1.0f;   // deg = in-degree + 1 (self loop)
        dinv[i]    = rsqrtf(d);
        deg_inv[i] = 1.0f / d;
    }
}

// inclusive scan of each 256-tile; tile totals to bsums
__global__ void scan1_kernel(const int* __restrict__ deg, int* __restrict__ tmp,
                             int* __restrict__ bsums, int n) {
    __shared__ int s[256];
    int t = threadIdx.x;
    int i = blockIdx.x * 256 + t;
    int v = (i < n) ? deg[i] : 0;
    s[t] = v;
    __syncthreads();
    for (int o = 1; o < 256; o <<= 1) {
        int a = (t >= o) ? s[t - o] : 0;
        __syncthreads();
        s[t] += a;
        __syncthreads();
    }
    if (i < n) tmp[i] = s[t];
    if (t == 255) bsums[blockIdx.x] = s[t];
}

// exclusive scan of block sums (single block, nb <= 512)
__global__ void scan2_kernel(int* __restrict__ bsums, int nb) {
    __shared__ int s[512];
    int t = threadIdx.x;
    int v = (t < nb) ? bsums[t] : 0;
    s[t] = v;
    __syncthreads();
    for (int o = 1; o < 512; o <<= 1) {
        int a = (t >= o) ? s[t - o] : 0;
        __syncthreads();
        s[t] += a;
        __syncthreads();
    }
    if (t < nb) bsums[t] = s[t] - v;   // exclusive
}

__global__ void scan3_kernel(const int* __restrict__ tmp, const int* __restrict__ bsums,
                             const int* __restrict__ deg, int* __restrict__ row_ptr,
                             int* __restrict__ cursor, int n) {
    int b = blockIdx.x;
    int i = b * 256 + threadIdx.x;
    if (i < n) {
        int g  = tmp[i] + bsums[b];   // inclusive global
        int rp = g - deg[i];          // exclusive
        row_ptr[i] = rp;
        cursor[i]  = rp;
        if (i == n - 1) row_ptr[n] = g;
    }
}

__global__ void fill_edges_kernel(const int* __restrict__ src, const int* __restrict__ dst,
                                  const float* __restrict__ dinv, int* __restrict__ cursor,
                                  int* __restrict__ col, float* __restrict__ nrm, int e) {
    int i = blockIdx.x * 256 + threadIdx.x;
    if (i < e) {
        int s = src[i], d = dst[i];
        int pos = atomicAdd(&cursor[d], 1);
        col[pos] = s;
        nrm[pos] = dinv[s] * dinv[d];
    }
}

// ---------------- SpMM: out[i] = deg_inv[i]*in[i] + sum_e nrm[e]*in[col[e]] ----------------
// one wave per node, lane handles 2 consecutive floats (128 feats / 64 lanes)
__global__ __launch_bounds__(256) void spmm_kernel(const float* __restrict__ in,
                                                   float* __restrict__ out,
                                                   const int* __restrict__ row_ptr,
                                                   const int* __restrict__ col,
                                                   const float* __restrict__ nrm,
                                                   const float* __restrict__ deg_inv) {
    int wave = threadIdx.x >> 6;
    int node = blockIdx.x * 4 + wave;
    int lane = threadIdx.x & 63;
    if (node >= N_NODES) return;

    const float2* inp = (const float2*)in;
    float di = deg_inv[node];
    float2 xv = inp[node * 64 + lane];
    float2 acc;
    acc.x = di * xv.x;
    acc.y = di * xv.y;

    int e  = row_ptr[node];
    int e1 = row_ptr[node + 1];
    for (; e + 1 < e1; e += 2) {
        int   c0 = col[e],     c1 = col[e + 1];
        float w0 = nrm[e],     w1 = nrm[e + 1];
        float2 v0 = inp[c0 * 64 + lane];
        float2 v1 = inp[c1 * 64 + lane];
        acc.x += w0 * v0.x; acc.y += w0 * v0.y;
        acc.x += w1 * v1.x; acc.y += w1 * v1.y;
    }
    if (e < e1) {
        int   c = col[e];
        float w = nrm[e];
        float2 v = inp[c * 64 + lane];
        acc.x += w * v.x; acc.y += w * v.y;
    }
    ((float2*)out)[node * 64 + lane] = acc;
}

// ---------------- GEMM (in-place): Y[0:64 rows] = relu(Y @ W + b) ----------------
// block: 256 threads, tile 64 rows x 128 cols; Y tile staged in LDS (32 KiB);
// W (64 KiB) read from global (L1/L2 resident). Thread tile: 8 rows x 4 cols.
__global__ __launch_bounds__(256) void gemm_bias_relu_kernel(float* __restrict__ Y,
                                                             const float* __restrict__ W,
                                                             const float* __restrict__ bias) {
    __shared__ float Yl[64 * 128];
    const int tid  = threadIdx.x;
    const int row0 = blockIdx.x * 64;

    // stage 64x128 tile, coalesced float4
#pragma unroll
    for (int m = 0; m < 8; ++m) {
        int lin = tid + m * 256;            // 0..2047
        int r   = lin >> 5;                 // 0..63
        int k4  = (lin & 31) << 2;          // 0..124
        int gr  = row0 + r;
        float4 v = make_float4(0.f, 0.f, 0.f, 0.f);
        if (gr < N_NODES) v = *(const float4*)&Y[gr * 128 + k4];
        *(float4*)&Yl[r * 128 + k4] = v;
    }
    __syncthreads();

    const int jg = (tid & 31) << 2;         // 4 consecutive output cols
    const int rg = (tid >> 5) << 3;         // 8 rows

    float acc[8][4];
#pragma unroll
    for (int r = 0; r < 8; ++r)
#pragma unroll
        for (int j = 0; j < 4; ++j) acc[r][j] = 0.f;

#pragma unroll 2
    for (int k0 = 0; k0 < 128; k0 += 4) {
        float4 w0 = *(const float4*)&W[(k0 + 0) * 128 + jg];
        float4 w1 = *(const float4*)&W[(k0 + 1) * 128 + jg];
        float4 w2 = *(const float4*)&W[(k0 + 2) * 128 + jg];
        float4 w3 = *(const float4*)&W[(k0 + 3) * 128 + jg];
#pragma unroll
        for (int r = 0; r < 8; ++r) {
            float4 y = *(const float4*)&Yl[(rg + r) * 128 + k0];
            acc[r][0] += y.x * w0.x + y.y * w1.x + y.z * w2.x + y.w * w3.x;
            acc[r][1] += y.x * w0.y + y.y * w1.y + y.z * w2.y + y.w * w3.y;
            acc[r][2] += y.x * w0.z + y.y * w1.z + y.z * w2.z + y.w * w3.z;
            acc[r][3] += y.x * w0.w + y.y * w1.w + y.z * w2.w + y.w * w3.w;
        }
    }

    float4 b4 = *(const float4*)&bias[jg];
    // in-place write is safe: compute reads only the LDS copy
#pragma unroll
    for (int r = 0; r < 8; ++r) {
        int gr = row0 + rg + r;
        if (gr < N_NODES) {
            float4 o;
            o.x = fmaxf(acc[r][0] + b4.x, 0.f);
            o.y = fmaxf(acc[r][1] + b4.y, 0.f);
            o.z = fmaxf(acc[r][2] + b4.z, 0.f);
            o.w = fmaxf(acc[r][3] + b4.w, 0.f);
            *(float4*)&Y[gr * 128 + jg] = o;
        }
    }
}

// ---------------- mean pool over sorted batch ids ----------------
__global__ void pool_kernel(const float* __restrict__ H, const int* __restrict__ batch,
                            float* __restrict__ pooled) {
    int g = blockIdx.x;
    int t = threadIdx.x;   // 128 threads, one per feature

    // lower_bound(batch, g) and lower_bound(batch, g+1)
    int lo = 0, hi = N_NODES;
    while (lo < hi) { int mid = (lo + hi) >> 1; if (batch[mid] < g) lo = mid + 1; else hi = mid; }
    int start = lo;
    lo = start; hi = N_NODES;
    while (lo < hi) { int mid = (lo + hi) >> 1; if (batch[mid] < g + 1) lo = mid + 1; else hi = mid; }
    int end = lo;

    float acc = 0.f;
    for (int n = start; n < end; ++n) acc += H[n * 128 + t];
    float cnt = (float)(end - start);
    pooled[g * 128 + t] = acc / fmaxf(cnt, 1.0f);
}

// ---------------- classifier head: relu(pooled @ Wc1 + bc1) @ Wc2 + bc2 ----------------
__global__ void classify_kernel(const float* __restrict__ pooled,
                                const float* __restrict__ Wc1, const float* __restrict__ bc1,
                                const float* __restrict__ Wc2, const float* __restrict__ bc2,
                                float* __restrict__ out) {
    __shared__ float p[128];
    __shared__ float z[64];
    int g = blockIdx.x;
    int t = threadIdx.x;   // 64 threads
    p[t]      = pooled[g * 128 + t];
    p[t + 64] = pooled[g * 128 + t + 64];
    __syncthreads();
    float a = bc1[t];
#pragma unroll 4
    for (int k = 0; k < 128; ++k) a += p[k] * Wc1[k * 64 + t];
    z[t] = fmaxf(a, 0.f);
    __syncthreads();
    if (t < 8) {
        float o = bc2[t];
#pragma unroll 8
        for (int j = 0; j < 64; ++j) o += z[j] * Wc2[j * 8 + t];
        out[g * 8 + t] = o;
    }
}

// ---------------- launch ----------------

extern "C" void kernel_launch(void* const* d_in, const int* in_sizes, int n_in,
                              void* d_out, int out_size, void* d_ws, size_t ws_size,
                              hipStream_t stream) {
    const float* x    = (const float*)d_in[0];
    const int*   ei   = (const int*)d_in[1];       // [2][E]
    const int*   bat  = (const int*)d_in[2];
    const float* W1   = (const float*)d_in[3];
    const float* b1   = (const float*)d_in[4];
    const float* W2   = (const float*)d_in[5];
    const float* b2   = (const float*)d_in[6];
    const float* W3   = (const float*)d_in[7];
    const float* b3   = (const float*)d_in[8];
    const float* Wc1  = (const float*)d_in[9];
    const float* bc1  = (const float*)d_in[10];
    const float* Wc2  = (const float*)d_in[11];
    const float* bc2  = (const float*)d_in[12];
    float* out = (float*)d_out;

    const int* src = ei;
    const int* dst = ei + N_EDGES;

    // workspace carve-up (256B aligned)
    char* base = (char*)d_ws;
    size_t off = 0;
    auto alloc = [&](size_t bytes) -> void* {
        void* p = base + off;
        off = (off + bytes + 255) & ~(size_t)255;
        return p;
    };
    int*   deg_int = (int*)  alloc((size_t)N_NODES * 4);
    int*   tmp     = (int*)  alloc((size_t)N_NODES * 4);
    int*   bsums   = (int*)  alloc(512 * 4);
    int*   row_ptr = (int*)  alloc(((size_t)N_NODES + 1) * 4);
    int*   cursor  = (int*)  alloc((size_t)N_NODES * 4);
    float* dinv    = (float*)alloc((size_t)N_NODES * 4);
    float* deg_inv = (float*)alloc((size_t)N_NODES * 4);
    int*   colA    = (int*)  alloc((size_t)N_EDGES * 4);
    float* nrmA    = (float*)alloc((size_t)N_EDGES * 4);
    float* bufA    = (float*)alloc((size_t)N_NODES * 128 * 4);
    float* bufB    = (float*)alloc((size_t)N_NODES * 128 * 4);
    float* pooled  = (float*)alloc((size_t)NG * 128 * 4);
    (void)ws_size; (void)n_in; (void)in_sizes; (void)out_size;

    const int nTilesN  = (N_NODES + 255) / 256;   // 391
    const int nBlocksE = (N_EDGES + 255) / 256;   // 6250

    // CSR build
    hipLaunchKernelGGL(zero_int_kernel, dim3(nTilesN), dim3(256), 0, stream, deg_int, N_NODES);
    hipLaunchKernelGGL(count_deg_kernel, dim3(nBlocksE), dim3(256), 0, stream, dst, deg_int, N_EDGES);
    hipLaunchKernelGGL(node_scalars_kernel, dim3(nTilesN), dim3(256), 0, stream, deg_int, dinv, deg_inv, N_NODES);
    hipLaunchKernelGGL(scan1_kernel, dim3(nTilesN), dim3(256), 0, stream, deg_int, tmp, bsums, N_NODES);
    hipLaunchKernelGGL(scan2_kernel, dim3(1), dim3(512), 0, stream, bsums, nTilesN);
    hipLaunchKernelGGL(scan3_kernel, dim3(nTilesN), dim3(256), 0, stream, tmp, bsums, deg_int, row_ptr, cursor, N_NODES);
    hipLaunchKernelGGL(fill_edges_kernel, dim3(nBlocksE), dim3(256), 0, stream, src, dst, dinv, cursor, colA, nrmA, N_EDGES);

    const int spmmGrid = N_NODES / 4;            // 25000 (exact)
    const int gemmGrid = (N_NODES + 63) / 64;    // 1563

    // layer 1
    hipLaunchKernelGGL(spmm_kernel, dim3(spmmGrid), dim3(256), 0, stream, x,    bufA, row_ptr, colA, nrmA, deg_inv);
    hipLaunchKernelGGL(gemm_bias_relu_kernel, dim3(gemmGrid), dim3(256), 0, stream, bufA, W1, b1);
    // layer 2
    hipLaunchKernelGGL(spmm_kernel, dim3(spmmGrid), dim3(256), 0, stream, bufA, bufB, row_ptr, colA, nrmA, deg_inv);
    hipLaunchKernelGGL(gemm_bias_relu_kernel, dim3(gemmGrid), dim3(256), 0, stream, bufB, W2, b2);
    // layer 3
    hipLaunchKernelGGL(spmm_kernel, dim3(spmmGrid), dim3(256), 0, stream, bufB, bufA, row_ptr, colA, nrmA, deg_inv);
    hipLaunchKernelGGL(gemm_bias_relu_kernel, dim3(gemmGrid), dim3(256), 0, stream, bufA, W3, b3);

    // pool + classifier
    hipLaunchKernelGGL(pool_kernel, dim3(NG), dim3(128), 0, stream, bufA, bat, pooled);
    hipLaunchKernelGGL(classify_kernel, dim3(NG), dim3(64), 0, stream, pooled, Wc1, bc1, Wc2, bc2, out);
}